// Round 6
// baseline (83.626 us; speedup 1.0000x reference)
//
#include <hip/hip_runtime.h>

// ---------------- problem constants ----------------
#define HW     262144      // 512*512
#define NB     4
#define NID    15
#define KB     256         // lovasz buckets; approx err <= (2/KB)*sum|dJ| ~ 0.008 << 1.045 thr
#define CHUNKS 128         // hist chunk-splits per image
#define PXC    (HW / CHUNKS)   // 2048 px per hist block

// ---------------- workspace layout (float offsets) ----------------
#define WS_TICKET 0        // 1 uint: last-block ticket (zeroed by K1)
#define WS_GACC   4        // [NB][5] atomic accums: obj, inst, var, intra, seed (zeroed by K1)
#define WS_SBGR   24       // [NB] reduced seed_bg (written by K2 chunk==0 blocks)
#define WS_PART   64       // [61][1024] component-major per-block stat partials (plain stores)
#define PART_STR  1024
#define WS_FACC   65600    // [NB*CHUNKS][48] per-block fg-accum partials (plain stores)
#define WS_HIST   90432    // u32 [NB][CHUNKS][NID][KB], packed fg | bg<<16
#define HIST_U32  (NB * CHUNKS * NID * KB)   // 1,966,080
#define WS_EMBX   (WS_HIST + HIST_U32)
#define MAP_SZ    (NB * HW)
#define WS_EMBY   (WS_EMBX + MAP_SZ)
#define WS_SEEDM  (WS_EMBY + MAP_SZ)
#define WS_TOTAL  (WS_SEEDM + MAP_SZ)        // ~20.8 MB << 256 MB ws

__device__ __forceinline__ float rcp_fast(float x) { return __builtin_amdgcn_rcpf(x); }
__device__ __forceinline__ float fast_tanh(float x) {
    return 1.0f - 2.0f * rcp_fast(__expf(2.0f * x) + 1.0f);   // inf-safe
}
__device__ __forceinline__ float fast_sigmoid(float x) {
    return rcp_fast(1.0f + __expf(-x));
}
__device__ __forceinline__ float atomic_read(float* p) { return atomicAdd(p, 0.0f); }

// ---------------- kernel 1: maps + per-block stat partials (no atomics, no pre-zero) ----
// grid (256, NB), 256 threads, 4 px/thread. LDS 16-copy accumulation, then each
// block stores its 61 partials to distinct slots: ws[WS_PART + c*1024 + b*256 + bx].
// Block (0,0) also zeroes the ticket + 20 global accumulators for kernel 3.
__global__ __launch_bounds__(256) void prepKernel(const float* __restrict__ pred,
                                                  const int* __restrict__ inst,
                                                  const int* __restrict__ lab,
                                                  float* __restrict__ ws) {
    __shared__ float s_acc[16][68];   // [group][(i*4+c) | 60=seed_bg]
    const int b   = blockIdx.y;
    const int tid = threadIdx.x;
    for (int j = tid; j < 16 * 68; j += 256) ((float*)s_acc)[j] = 0.f;
    __syncthreads();

    const int grp = tid >> 4;
    const int ib = b * HW;
    const float* p0 = pred + (((size_t)(b * 4 + 0)) << 18);
    const float* p1 = pred + (((size_t)(b * 4 + 1)) << 18);
    const float* p2 = pred + (((size_t)(b * 4 + 2)) << 18);
    const float* p3 = pred + (((size_t)(b * 4 + 3)) << 18);
    float* embx  = ws + WS_EMBX + ib;
    float* emby  = ws + WS_EMBY + ib;
    float* seedm = ws + WS_SEEDM + ib;
    const float inv511 = 1.0f / 511.0f;

    const int p = blockIdx.x * 1024 + tid * 4;
    const int4   i4 = *(const int4*)(inst + ib + p);
    const int4   l4 = *(const int4*)(lab + ib + p);
    const float4 a4 = *(const float4*)(p0 + p);
    const float4 b4 = *(const float4*)(p1 + p);
    const float4 g4 = *(const float4*)(p2 + p);
    const float4 t4 = *(const float4*)(p3 + p);
    const float xs0 = (float)(p & 511) * inv511;
    const float ys  = (float)(p >> 9) * inv511;

    float4 ex, ey, sd;
    ex.x = fast_tanh(a4.x) + xs0;
    ex.y = fast_tanh(a4.y) + xs0 + inv511;
    ex.z = fast_tanh(a4.z) + xs0 + 2.f * inv511;
    ex.w = fast_tanh(a4.w) + xs0 + 3.f * inv511;
    ey.x = fast_tanh(b4.x) + ys;
    ey.y = fast_tanh(b4.y) + ys;
    ey.z = fast_tanh(b4.z) + ys;
    ey.w = fast_tanh(b4.w) + ys;
    sd.x = fast_sigmoid(t4.x);
    sd.y = fast_sigmoid(t4.y);
    sd.z = fast_sigmoid(t4.z);
    sd.w = fast_sigmoid(t4.w);
    *(float4*)(embx + p)  = ex;
    *(float4*)(emby + p)  = ey;
    *(float4*)(seedm + p) = sd;

    float sbg = 0.f;
    sbg += (l4.x == 0) ? sd.x * sd.x : 0.f;
    sbg += (l4.y == 0) ? sd.y * sd.y : 0.f;
    sbg += (l4.z == 0) ? sd.z * sd.z : 0.f;
    sbg += (l4.w == 0) ? sd.w * sd.w : 0.f;

#define ACC_PX(IID, XS, SG)                                   \
    if ((IID) > 0) {                                          \
        float* a = &s_acc[grp][((IID) - 1) * 4];              \
        atomicAdd(a + 0, 1.f);                                \
        atomicAdd(a + 1, (XS));                               \
        atomicAdd(a + 2, ys);                                 \
        atomicAdd(a + 3, (SG));                               \
    }
    ACC_PX(i4.x, xs0, g4.x)
    ACC_PX(i4.y, xs0 + inv511, g4.y)
    ACC_PX(i4.z, xs0 + 2.f * inv511, g4.z)
    ACC_PX(i4.w, xs0 + 3.f * inv511, g4.w)
#undef ACC_PX

#pragma unroll
    for (int m = 32; m; m >>= 1) sbg += __shfl_xor(sbg, m, 64);
    if ((tid & 63) == 0) atomicAdd(&s_acc[grp][60], sbg);
    __syncthreads();

    if (tid < 61) {
        float tot = 0.f;
#pragma unroll
        for (int q = 0; q < 16; ++q) tot += s_acc[q][tid];
        ws[WS_PART + tid * PART_STR + b * 256 + blockIdx.x] = tot;   // distinct slot
    }
    if (blockIdx.x == 0 && b == 0) {
        if (tid < 20)       ws[WS_GACC + tid] = 0.f;
        else if (tid == 20) ((unsigned*)ws)[WS_TICKET] = 0u;
    }
}

// ---------------- kernel 2: stat-reduce + all-ids histogram + fg sums ----------------
// grid (CHUNKS, NB) = 512 blocks (2/CU). Phase 0: reduce the 256 stat partials
// for image b (contiguous loads). Main: per pixel, all 15 ids into 4 lane-group
// LDS hist copies (packed fg|bg<<16). Flush: plain coalesced stores only.
#define HCOPY_STRIDE (NID * KB + 1)    // 3841 words: de-bank the copies
__global__ __launch_bounds__(256) void histKernel(const float* __restrict__ pred,
                                                  const int* __restrict__ inst,
                                                  float* __restrict__ ws) {
    __shared__ unsigned s_hist[4 * HCOPY_STRIDE];   // 61456 B
    __shared__ float4   s_stat4[NID];               // cx, cy, sigm, s
    __shared__ float    s_facc[8][48];              // fg accum copies
    __shared__ float    s_comp[61];

    const int b     = blockIdx.y;
    const int chunk = blockIdx.x;
    const int tid   = threadIdx.x;
    const int wv = tid >> 6, lane = tid & 63;

    // phase 0: reduce per-block partials -> s_comp[61]
    for (int c = wv; c < 61; c += 4) {
        const float* pp = ws + WS_PART + c * PART_STR + b * 256;
        float v = pp[lane] + pp[lane + 64] + pp[lane + 128] + pp[lane + 192];
#pragma unroll
        for (int m = 32; m; m >>= 1) v += __shfl_xor(v, m, 64);
        if (lane == 0) s_comp[c] = v;
    }
    for (int j = tid; j < 4 * HCOPY_STRIDE; j += 256) s_hist[j] = 0u;
    for (int j = tid; j < 8 * 48; j += 256) ((float*)s_facc)[j] = 0.f;
    __syncthreads();

    if (tid < NID) {
        float cnt = s_comp[tid * 4 + 0];
        float ic = rcp_fast(fmaxf(cnt, 1.f));
        float sigm = s_comp[tid * 4 + 3] * ic;
        s_stat4[tid] = make_float4(s_comp[tid * 4 + 1] * ic, s_comp[tid * 4 + 2] * ic,
                                   sigm, __expf(10.f * sigm));
    }
    if (chunk == 0 && tid == 16) ws[WS_SBGR + b] = s_comp[60];  // publish seed_bg
    __syncthreads();

    float csx[NID], csy[NID], css[NID];
#pragma unroll
    for (int i = 0; i < NID; ++i) {
        float4 v = s_stat4[i];
        csx[i] = v.x; csy[i] = v.y; css[i] = v.w;
    }

    unsigned* myhist = &s_hist[((tid >> 4) & 3) * HCOPY_STRIDE];
    float* myfacc = s_facc[(tid >> 3) & 7];
    const int ib = b * HW;
    const float* sig   = pred + (((size_t)(b * 4 + 2)) << 18);
    const float* embx  = ws + WS_EMBX + ib;
    const float* emby  = ws + WS_EMBY + ib;
    const float* seedm = ws + WS_SEEDM + ib;

    auto doPx = [&](float exv, float eyv, float sdv, float gv, int iid) {
#pragma unroll
        for (int i = 0; i < NID; ++i) {
            float dx = exv - csx[i], dy = eyv - csy[i];
            float dist = __expf(-(dx * dx + dy * dy) * css[i]);
            float u1 = dist * (float)KB;
            bool m = (iid == i + 1);
            float bf = m ? ((float)KB - u1) : u1;
            int bk = min((int)bf, KB - 1);
            atomicAdd(&myhist[i * KB + bk], m ? 1u : 0x10000u);
        }
        if (iid > 0) {
            float4 st = s_stat4[iid - 1];
            float dx = exv - st.x, dy = eyv - st.y;
            float dist = __expf(-(dx * dx + dy * dy) * st.w);
            float dsg = gv - st.z;
            float e2 = sdv - dist;
            float* fa = &myfacc[(iid - 1) * 3];
            atomicAdd(fa + 0, dsg * dsg);
            atomicAdd(fa + 1, e2 * e2);
            atomicAdd(fa + 2, dist);
        }
    };

#pragma unroll
    for (int u = 0; u < 2; ++u) {
        const int p = chunk * PXC + u * 1024 + tid * 4;
        const int4   i4 = *(const int4*)(inst + ib + p);
        const float4 exq = *(const float4*)(embx + p);
        const float4 eyq = *(const float4*)(emby + p);
        const float4 sdq = *(const float4*)(seedm + p);
        const float4 gq  = *(const float4*)(sig + p);
        doPx(exq.x, eyq.x, sdq.x, gq.x, i4.x);
        doPx(exq.y, eyq.y, sdq.y, gq.y, i4.y);
        doPx(exq.z, eyq.z, sdq.z, gq.z, i4.z);
        doPx(exq.w, eyq.w, sdq.w, gq.w, i4.w);
    }
    __syncthreads();

    // flush hist: sum 4 copies, plain coalesced stores
    unsigned* dst = (unsigned*)(ws + WS_HIST) + (size_t)(b * CHUNKS + chunk) * (NID * KB);
    for (int j = tid; j < NID * KB; j += 256) {
        dst[j] = s_hist[j] + s_hist[HCOPY_STRIDE + j] +
                 s_hist[2 * HCOPY_STRIDE + j] + s_hist[3 * HCOPY_STRIDE + j];
    }
    // flush fg accums: distinct per-block slots, plain stores
    if (tid < 45) {
        float tot = 0.f;
#pragma unroll
        for (int q = 0; q < 8; ++q) tot += s_facc[q][tid];
        ws[WS_FACC + (size_t)(b * CHUNKS + chunk) * 48 + tid] = tot;
    }
}

// ---------------- kernel 3: Lovász scan + per-image accumulate + last-block final ------
// 60 blocks x 256 threads. Each block: reduce G + fg sums, chunk-sum its hist,
// suffix-scan, atomicAdd 5 contributions into ws[WS_GACC + b*5..]. Last block
// (ticket==59) composes the output scalar.
__global__ __launch_bounds__(256) void lovaszKernel(float* __restrict__ ws,
                                                    float* __restrict__ out) {
    __shared__ unsigned s_pf[4][KB];
    __shared__ unsigned s_pb[4][KB];
    __shared__ float s4[4];
    __shared__ float s_f[4][3];
    const int t = blockIdx.x;           // b*15+i
    const int b = t / NID, i = t % NID;
    const int tid = threadIdx.x, wv = tid >> 6, lane = tid & 63;

    // G = count for (b,i): reduce 256 contiguous partials of component i*4
    {
        float g = ws[WS_PART + (i * 4) * PART_STR + b * 256 + tid];
#pragma unroll
        for (int m = 32; m; m >>= 1) g += __shfl_xor(g, m, 64);
        if (lane == 0) s4[wv] = g;
    }
    // fg sums: 128 chunk partials, 3 components
    {
        float f0 = 0.f, f1 = 0.f, f2 = 0.f;
        if (tid < CHUNKS) {
            const float* fb = ws + WS_FACC + (size_t)(b * CHUNKS + tid) * 48 + i * 3;
            f0 = fb[0]; f1 = fb[1]; f2 = fb[2];
        }
#pragma unroll
        for (int m = 32; m; m >>= 1) {
            f0 += __shfl_xor(f0, m, 64);
            f1 += __shfl_xor(f1, m, 64);
            f2 += __shfl_xor(f2, m, 64);
        }
        if (lane == 0) { s_f[wv][0] = f0; s_f[wv][1] = f1; s_f[wv][2] = f2; }
    }
    __syncthreads();
    const float G = s4[0] + s4[1] + s4[2] + s4[3];

    if (G > 0.f) {
        unsigned af0 = 0, af1 = 0, af2 = 0, af3 = 0;
        unsigned ab0 = 0, ab1 = 0, ab2 = 0, ab3 = 0;
        const unsigned* histU = (const unsigned*)(ws + WS_HIST);
        for (int k = 0; k < 32; ++k) {
            const int c = wv * 32 + k;
            const unsigned* hb = histU + ((size_t)(b * CHUNKS + c) * NID + i) * KB + lane * 4;
            uint4 q = *(const uint4*)hb;
            af0 += q.x & 0xffffu; ab0 += q.x >> 16;
            af1 += q.y & 0xffffu; ab1 += q.y >> 16;
            af2 += q.z & 0xffffu; ab2 += q.z >> 16;
            af3 += q.w & 0xffffu; ab3 += q.w >> 16;
        }
        s_pf[wv][lane * 4 + 0] = af0; s_pb[wv][lane * 4 + 0] = ab0;
        s_pf[wv][lane * 4 + 1] = af1; s_pb[wv][lane * 4 + 1] = ab1;
        s_pf[wv][lane * 4 + 2] = af2; s_pb[wv][lane * 4 + 2] = ab2;
        s_pf[wv][lane * 4 + 3] = af3; s_pb[wv][lane * 4 + 3] = ab3;
    }
    __syncthreads();

    float sum = 0.f;
    if (wv == 0 && G > 0.f) {
        float fgs[4], bgs[4];
#pragma unroll
        for (int q = 0; q < 4; ++q) {
            int k = lane * 4 + q;
            fgs[q] = (float)(s_pf[0][k] + s_pf[1][k] + s_pf[2][k] + s_pf[3][k]);
            bgs[q] = (float)(s_pb[0][k] + s_pb[1][k] + s_pb[2][k] + s_pb[3][k]);
        }
        float Fl = fgs[0] + fgs[1] + fgs[2] + fgs[3];
        float Bl = bgs[0] + bgs[1] + bgs[2] + bgs[3];
        float Fs = Fl, Bs = Bl;
#pragma unroll
        for (int d = 1; d < 64; d <<= 1) {
            float fu = __shfl_down(Fs, d, 64);
            float bu = __shfl_down(Bs, d, 64);
            if (lane + d < 64) { Fs += fu; Bs += bu; }
        }
        float F = Fs - Fl, B = Bs - Bl;        // totals strictly above this lane's segment
        float Jprev = 1.f - (G - F) * rcp_fast(G + B);
        const float ew = 2.f / (float)KB;
#pragma unroll
        for (int q = 3; q >= 0; --q) {
            F += fgs[q]; B += bgs[q];
            float J = 1.f - (G - F) * rcp_fast(G + B);
            float ek = ((float)(lane * 4 + q) + 0.5f) * ew;
            sum += ek * (J - Jprev);
            Jprev = J;
        }
#pragma unroll
        for (int m = 32; m; m >>= 1) sum += __shfl_xor(sum, m, 64);
    }

    if (tid == 0 && G > 0.f) {
        float ic = rcp_fast(fmaxf(G, 1.f));
        float F0 = s_f[0][0] + s_f[1][0] + s_f[2][0] + s_f[3][0];   // var sum
        float F1 = s_f[0][1] + s_f[1][1] + s_f[2][1] + s_f[3][1];   // seed sum
        float F2 = s_f[0][2] + s_f[1][2] + s_f[2][2] + s_f[3][2];   // dist sum
        float* ga = ws + WS_GACC + b * 5;
        atomicAdd(ga + 0, 1.f);            // obj count
        atomicAdd(ga + 1, sum);            // instance (lovasz)
        atomicAdd(ga + 2, F0 * ic);        // var
        atomicAdd(ga + 3, 1.f - F2 * ic);  // intra
        atomicAdd(ga + 4, F1);             // seed fg
    }
    __threadfence();
    if (tid == 0) {
        unsigned tk = atomicAdd((unsigned*)ws + WS_TICKET, 1u);
        if (tk == 59u) {
            float total = 0.f;
            for (int bb = 0; bb < NB; ++bb) {
                float* ga = ws + WS_GACC + bb * 5;
                float obj   = atomic_read(ga + 0);
                float instl = atomic_read(ga + 1);
                float varl  = atomic_read(ga + 2);
                float intral= atomic_read(ga + 3);
                float seedl = atomic_read(ga + 4);
                float sbg   = ws[WS_SBGR + bb];      // K2 data: kernel-boundary visible
                float objs  = fmaxf(obj, 1.f);
                total += instl / objs
                       + 10.f * (varl / objs)
                       + (sbg + seedl) / (float)HW
                       + 5.f * intral;
            }
            out[0] = total * 0.25f;
        }
    }
}

extern "C" void kernel_launch(void* const* d_in, const int* in_sizes, int n_in,
                              void* d_out, int out_size, void* d_ws, size_t ws_size,
                              hipStream_t stream) {
    const float* pred = (const float*)d_in[0];
    const int*   inst = (const int*)d_in[1];
    const int*   lab  = (const int*)d_in[2];
    float* ws  = (float*)d_ws;
    float* out = (float*)d_out;

    prepKernel<<<dim3(256, NB), 256, 0, stream>>>(pred, inst, lab, ws);
    histKernel<<<dim3(CHUNKS, NB), 256, 0, stream>>>(pred, inst, ws);
    lovaszKernel<<<60, 256, 0, stream>>>(ws, out);
}

// Round 7
// 82.246 us; speedup vs baseline: 1.0168x; 1.0168x over previous
//
#include <hip/hip_runtime.h>

// ---------------- problem constants ----------------
#define HW     262144      // 512*512
#define NB     4
#define NID    15
#define KB     128         // lovasz buckets; approx err <= (2/KB)*TV(J) ~ 0.016 << 1.045 thr
#define CHUNKS 256         // hist chunk-splits per image
#define PXC    (HW / CHUNKS)   // 1024 px per hist block

// ---------------- workspace layout (float offsets) ----------------
#define WS_TICKET 0        // 1 uint (zeroed by statRed)
#define WS_GACC   4        // [NB][5] atomic accums (zeroed by statRed)
#define WS_SBG    24       // [NB] seed_bg
#define WS_CNT    28       // [60] instance counts
#define WS_STAT4  96       // [60][4]: cx, cy, sigm, s*log2e
#define WS_PART   512      // [61][1024] component-major per-block stat partials
#define PART_STR  1024
#define WS_FACC   62976    // [NB*CHUNKS][48] per-block fg-accum partials
#define WS_HIST   112128   // u32 [NB][CHUNKS][NID][KB], packed fg | bg<<16
#define HIST_U32  (NB * CHUNKS * NID * KB)   // 1,966,080
#define WS_EMBX   (WS_HIST + HIST_U32)
#define MAP_SZ    (NB * HW)
#define WS_EMBY   (WS_EMBX + MAP_SZ)
#define WS_SEEDM  (WS_EMBY + MAP_SZ)
#define WS_TOTAL  (WS_SEEDM + MAP_SZ)        // ~20.9 MB << 256 MB ws

#if __has_builtin(__builtin_amdgcn_exp2f)
#define EXP2(x) __builtin_amdgcn_exp2f(x)
#else
#define EXP2(x) exp2f(x)
#endif
#define LOG2E 1.44269504f

__device__ __forceinline__ float rcp_fast(float x) { return __builtin_amdgcn_rcpf(x); }
__device__ __forceinline__ float fast_tanh(float x) {
    // 1 - 2/(2^(2x*log2e)+1): inf-safe
    return 1.0f - 2.0f * rcp_fast(EXP2(2.0f * LOG2E * x) + 1.0f);
}
__device__ __forceinline__ float fast_sigmoid(float x) {
    return rcp_fast(1.0f + EXP2(-LOG2E * x));
}
__device__ __forceinline__ float atomic_read(float* p) { return atomicAdd(p, 0.0f); }

// ---------------- kernel 1: maps + per-block stat partials (plain stores) ----------
// grid (256, NB) = 1024 blocks, 4 px/thread.
__global__ __launch_bounds__(256) void prepKernel(const float* __restrict__ pred,
                                                  const int* __restrict__ inst,
                                                  const int* __restrict__ lab,
                                                  float* __restrict__ ws) {
    __shared__ float s_acc[16][68];   // [group][(i*4+c) | 60=seed_bg]
    const int b   = blockIdx.y;
    const int tid = threadIdx.x;
    for (int j = tid; j < 16 * 68; j += 256) ((float*)s_acc)[j] = 0.f;
    __syncthreads();

    const int grp = tid >> 4;
    const int ib = b * HW;
    const float* p0 = pred + (((size_t)(b * 4 + 0)) << 18);
    const float* p1 = pred + (((size_t)(b * 4 + 1)) << 18);
    const float* p2 = pred + (((size_t)(b * 4 + 2)) << 18);
    const float* p3 = pred + (((size_t)(b * 4 + 3)) << 18);
    float* embx  = ws + WS_EMBX + ib;
    float* emby  = ws + WS_EMBY + ib;
    float* seedm = ws + WS_SEEDM + ib;
    const float inv511 = 1.0f / 511.0f;

    const int p = blockIdx.x * 1024 + tid * 4;
    const int4   i4 = *(const int4*)(inst + ib + p);
    const int4   l4 = *(const int4*)(lab + ib + p);
    const float4 a4 = *(const float4*)(p0 + p);
    const float4 b4 = *(const float4*)(p1 + p);
    const float4 g4 = *(const float4*)(p2 + p);
    const float4 t4 = *(const float4*)(p3 + p);
    const float xs0 = (float)(p & 511) * inv511;
    const float ys  = (float)(p >> 9) * inv511;

    float4 ex, ey, sd;
    ex.x = fast_tanh(a4.x) + xs0;
    ex.y = fast_tanh(a4.y) + xs0 + inv511;
    ex.z = fast_tanh(a4.z) + xs0 + 2.f * inv511;
    ex.w = fast_tanh(a4.w) + xs0 + 3.f * inv511;
    ey.x = fast_tanh(b4.x) + ys;
    ey.y = fast_tanh(b4.y) + ys;
    ey.z = fast_tanh(b4.z) + ys;
    ey.w = fast_tanh(b4.w) + ys;
    sd.x = fast_sigmoid(t4.x);
    sd.y = fast_sigmoid(t4.y);
    sd.z = fast_sigmoid(t4.z);
    sd.w = fast_sigmoid(t4.w);
    *(float4*)(embx + p)  = ex;
    *(float4*)(emby + p)  = ey;
    *(float4*)(seedm + p) = sd;

    float sbg = 0.f;
    sbg += (l4.x == 0) ? sd.x * sd.x : 0.f;
    sbg += (l4.y == 0) ? sd.y * sd.y : 0.f;
    sbg += (l4.z == 0) ? sd.z * sd.z : 0.f;
    sbg += (l4.w == 0) ? sd.w * sd.w : 0.f;

#define ACC_PX(IID, XS, SG)                                   \
    if ((IID) > 0) {                                          \
        float* a = &s_acc[grp][((IID) - 1) * 4];              \
        atomicAdd(a + 0, 1.f);                                \
        atomicAdd(a + 1, (XS));                               \
        atomicAdd(a + 2, ys);                                 \
        atomicAdd(a + 3, (SG));                               \
    }
    ACC_PX(i4.x, xs0, g4.x)
    ACC_PX(i4.y, xs0 + inv511, g4.y)
    ACC_PX(i4.z, xs0 + 2.f * inv511, g4.z)
    ACC_PX(i4.w, xs0 + 3.f * inv511, g4.w)
#undef ACC_PX

#pragma unroll
    for (int m = 32; m; m >>= 1) sbg += __shfl_xor(sbg, m, 64);
    if ((tid & 63) == 0) atomicAdd(&s_acc[grp][60], sbg);
    __syncthreads();

    if (tid < 61) {
        float tot = 0.f;
#pragma unroll
        for (int q = 0; q < 16; ++q) tot += s_acc[q][tid];
        ws[WS_PART + tid * PART_STR + b * 256 + blockIdx.x] = tot;
    }
}

// ---------------- kernel 1b: reduce stat partials; derive centers; zero accums ------
// grid (NB) = 4 blocks x 256 threads.
__global__ __launch_bounds__(256) void statRedKernel(float* __restrict__ ws) {
    __shared__ float s_red[61];
    const int b = blockIdx.x;
    const int tid = threadIdx.x, wv = tid >> 6, lane = tid & 63;

    for (int c = wv; c < 61; c += 4) {
        const float* pp = ws + WS_PART + c * PART_STR + b * 256;
        float v = pp[lane] + pp[lane + 64] + pp[lane + 128] + pp[lane + 192];
#pragma unroll
        for (int m = 32; m; m >>= 1) v += __shfl_xor(v, m, 64);
        if (lane == 0) s_red[c] = v;
    }
    __syncthreads();

    if (tid < NID) {
        float cnt = s_red[tid * 4 + 0];
        float ic = rcp_fast(fmaxf(cnt, 1.f));
        float sigm = s_red[tid * 4 + 3] * ic;
        // s' = exp(10*sigm)*log2e = 2^(10*log2e*sigm) * log2e
        float sp = EXP2(10.f * LOG2E * sigm) * LOG2E;
        *(float4*)(ws + WS_STAT4 + (b * NID + tid) * 4) =
            make_float4(s_red[tid * 4 + 1] * ic, s_red[tid * 4 + 2] * ic, sigm, sp);
        ws[WS_CNT + b * NID + tid] = cnt;
    }
    if (tid == 15) ws[WS_SBG + b] = s_red[60];
    if (b == 0) {
        if (tid >= 32 && tid < 52) ws[WS_GACC + tid - 32] = 0.f;
        if (tid == 52)             ((unsigned*)ws)[WS_TICKET] = 0u;
    }
}

// ---------------- kernel 2: all-ids histogram + fg sums ----------------
// grid (CHUNKS, NB) = 1024 blocks (4/CU, 16 waves/CU), 1024 px/block (4 px/thread).
// Packed fg|bg<<16 counts into 4 lane-group LDS copies. Flush = plain stores.
#define HCOPY_STRIDE (NID * KB + 1)    // 1921 words (odd): de-bank the copies
__global__ __launch_bounds__(256) void histKernel(const float* __restrict__ pred,
                                                  const int* __restrict__ inst,
                                                  float* __restrict__ ws) {
    __shared__ unsigned s_hist[4 * HCOPY_STRIDE];   // 30736 B
    __shared__ float4   s_stat4[NID];
    __shared__ float    s_facc[8][48];

    const int b     = blockIdx.y;
    const int chunk = blockIdx.x;
    const int tid   = threadIdx.x;

    if (tid < NID) s_stat4[tid] = *(const float4*)(ws + WS_STAT4 + (b * NID + tid) * 4);
    for (int j = tid; j < 4 * HCOPY_STRIDE; j += 256) s_hist[j] = 0u;
    for (int j = tid; j < 8 * 48; j += 256) ((float*)s_facc)[j] = 0.f;
    __syncthreads();

    float csx[NID], csy[NID], csp[NID];
#pragma unroll
    for (int i = 0; i < NID; ++i) {
        float4 v = s_stat4[i];
        csx[i] = v.x; csy[i] = v.y; csp[i] = v.w;
    }

    unsigned* myhist = &s_hist[((tid >> 4) & 3) * HCOPY_STRIDE];
    float* myfacc = s_facc[(tid >> 3) & 7];
    const int ib = b * HW;
    const float* sig   = pred + (((size_t)(b * 4 + 2)) << 18);
    const float* embx  = ws + WS_EMBX + ib;
    const float* emby  = ws + WS_EMBY + ib;
    const float* seedm = ws + WS_SEEDM + ib;

    auto doPx = [&](float exv, float eyv, float sdv, float gv, int iid) {
        float u1m = 0.f;
#pragma unroll
        for (int i = 0; i < NID; ++i) {
            float dx = exv - csx[i], dy = eyv - csy[i];
            float d2 = dx * dx + dy * dy;
            // u1 = dist*KB = 2^(7 - d2*s*log2e)
            float u1 = EXP2(7.0f - d2 * csp[i]);
            bool m = (iid == i + 1);
            if (m) u1m = u1;
            float bf = m ? ((float)KB - u1) : u1;
            int bk = min((int)bf, KB - 1);
            atomicAdd(&myhist[i * KB + bk], m ? 1u : 0x10000u);
        }
        if (iid > 0) {
            float dist = u1m * (1.f / (float)KB);
            float sigm = s_stat4[iid - 1].z;       // runtime LDS index: fine
            float dsg = gv - sigm;
            float e2 = sdv - dist;
            float* fa = &myfacc[(iid - 1) * 3];
            atomicAdd(fa + 0, dsg * dsg);
            atomicAdd(fa + 1, e2 * e2);
            atomicAdd(fa + 2, dist);
        }
    };

    const int p = chunk * PXC + tid * 4;
    const int4   i4 = *(const int4*)(inst + ib + p);
    const float4 exq = *(const float4*)(embx + p);
    const float4 eyq = *(const float4*)(emby + p);
    const float4 sdq = *(const float4*)(seedm + p);
    const float4 gq  = *(const float4*)(sig + p);
    doPx(exq.x, eyq.x, sdq.x, gq.x, i4.x);
    doPx(exq.y, eyq.y, sdq.y, gq.y, i4.y);
    doPx(exq.z, eyq.z, sdq.z, gq.z, i4.z);
    doPx(exq.w, eyq.w, sdq.w, gq.w, i4.w);
    __syncthreads();

    // flush hist: sum 4 copies, plain coalesced stores (counts <=1024: no overflow)
    unsigned* dst = (unsigned*)(ws + WS_HIST) + (size_t)(b * CHUNKS + chunk) * (NID * KB);
    for (int j = tid; j < NID * KB; j += 256) {
        dst[j] = s_hist[j] + s_hist[HCOPY_STRIDE + j] +
                 s_hist[2 * HCOPY_STRIDE + j] + s_hist[3 * HCOPY_STRIDE + j];
    }
    // flush fg accums: distinct per-block slots, plain stores
    if (tid < 45) {
        float tot = 0.f;
#pragma unroll
        for (int q = 0; q < 8; ++q) tot += s_facc[q][tid];
        ws[WS_FACC + (size_t)(b * CHUNKS + chunk) * 48 + tid] = tot;
    }
}

// ---------------- kernel 3: Lovász scan + per-image accumulate + last-block final ----
// 60 blocks x 256 threads. Wave wv sums chunks [64wv,64wv+64); wave 0 scans.
__global__ __launch_bounds__(256) void lovaszKernel(float* __restrict__ ws,
                                                    float* __restrict__ out) {
    __shared__ unsigned s_pf[4][KB];
    __shared__ unsigned s_pb[4][KB];
    __shared__ float s_f[4][3];
    const int t = blockIdx.x;           // b*15+i
    const int b = t / NID, i = t % NID;
    const int tid = threadIdx.x, wv = tid >> 6, lane = tid & 63;

    const float G = ws[WS_CNT + t];

    // fg sums: 256 chunk partials, 3 components
    {
        const float* fb = ws + WS_FACC + (size_t)(b * CHUNKS + tid) * 48 + i * 3;
        float f0 = fb[0], f1 = fb[1], f2 = fb[2];
#pragma unroll
        for (int m = 32; m; m >>= 1) {
            f0 += __shfl_xor(f0, m, 64);
            f1 += __shfl_xor(f1, m, 64);
            f2 += __shfl_xor(f2, m, 64);
        }
        if (lane == 0) { s_f[wv][0] = f0; s_f[wv][1] = f1; s_f[wv][2] = f2; }
    }

    if (G > 0.f) {
        unsigned af0 = 0, af1 = 0, ab0 = 0, ab1 = 0;
        const unsigned* histU = (const unsigned*)(ws + WS_HIST);
        for (int k = 0; k < 64; ++k) {
            const int c = wv * 64 + k;
            const unsigned* hb = histU + ((size_t)(b * CHUNKS + c) * NID + i) * KB + lane * 2;
            uint2 q = *(const uint2*)hb;
            af0 += q.x & 0xffffu; ab0 += q.x >> 16;
            af1 += q.y & 0xffffu; ab1 += q.y >> 16;
        }
        s_pf[wv][lane * 2 + 0] = af0; s_pb[wv][lane * 2 + 0] = ab0;
        s_pf[wv][lane * 2 + 1] = af1; s_pb[wv][lane * 2 + 1] = ab1;
    }
    __syncthreads();

    float sum = 0.f;
    if (wv == 0 && G > 0.f) {
        float fgs[2], bgs[2];
#pragma unroll
        for (int q = 0; q < 2; ++q) {
            int k = lane * 2 + q;
            fgs[q] = (float)(s_pf[0][k] + s_pf[1][k] + s_pf[2][k] + s_pf[3][k]);
            bgs[q] = (float)(s_pb[0][k] + s_pb[1][k] + s_pb[2][k] + s_pb[3][k]);
        }
        float Fl = fgs[0] + fgs[1];
        float Bl = bgs[0] + bgs[1];
        float Fs = Fl, Bs = Bl;
#pragma unroll
        for (int d = 1; d < 64; d <<= 1) {
            float fu = __shfl_down(Fs, d, 64);
            float bu = __shfl_down(Bs, d, 64);
            if (lane + d < 64) { Fs += fu; Bs += bu; }
        }
        float F = Fs - Fl, B = Bs - Bl;        // totals strictly above this lane's buckets
        float Jprev = 1.f - (G - F) * rcp_fast(G + B);
        const float ew = 2.f / (float)KB;
#pragma unroll
        for (int q = 1; q >= 0; --q) {         // descending k within lane
            F += fgs[q]; B += bgs[q];
            float J = 1.f - (G - F) * rcp_fast(G + B);
            float ek = ((float)(lane * 2 + q) + 0.5f) * ew;
            sum += ek * (J - Jprev);
            Jprev = J;
        }
#pragma unroll
        for (int m = 32; m; m >>= 1) sum += __shfl_xor(sum, m, 64);
    }

    if (tid == 0 && G > 0.f) {
        float ic = rcp_fast(fmaxf(G, 1.f));
        float F0 = s_f[0][0] + s_f[1][0] + s_f[2][0] + s_f[3][0];   // var sum
        float F1 = s_f[0][1] + s_f[1][1] + s_f[2][1] + s_f[3][1];   // seed sum
        float F2 = s_f[0][2] + s_f[1][2] + s_f[2][2] + s_f[3][2];   // dist sum
        float* ga = ws + WS_GACC + b * 5;
        atomicAdd(ga + 0, 1.f);
        atomicAdd(ga + 1, sum);
        atomicAdd(ga + 2, F0 * ic);
        atomicAdd(ga + 3, 1.f - F2 * ic);
        atomicAdd(ga + 4, F1);
    }
    __threadfence();
    if (tid == 0) {
        unsigned tk = atomicAdd((unsigned*)ws + WS_TICKET, 1u);
        if (tk == 59u) {
            float total = 0.f;
            for (int bb = 0; bb < NB; ++bb) {
                float* ga = ws + WS_GACC + bb * 5;
                float obj   = atomic_read(ga + 0);
                float instl = atomic_read(ga + 1);
                float varl  = atomic_read(ga + 2);
                float intral= atomic_read(ga + 3);
                float seedl = atomic_read(ga + 4);
                float sbg   = ws[WS_SBG + bb];
                float objs  = fmaxf(obj, 1.f);
                total += instl / objs
                       + 10.f * (varl / objs)
                       + (sbg + seedl) / (float)HW
                       + 5.f * intral;
            }
            out[0] = total * 0.25f;
        }
    }
}

extern "C" void kernel_launch(void* const* d_in, const int* in_sizes, int n_in,
                              void* d_out, int out_size, void* d_ws, size_t ws_size,
                              hipStream_t stream) {
    const float* pred = (const float*)d_in[0];
    const int*   inst = (const int*)d_in[1];
    const int*   lab  = (const int*)d_in[2];
    float* ws  = (float*)d_ws;
    float* out = (float*)d_out;

    prepKernel<<<dim3(256, NB), 256, 0, stream>>>(pred, inst, lab, ws);
    statRedKernel<<<NB, 256, 0, stream>>>(ws);
    histKernel<<<dim3(CHUNKS, NB), 256, 0, stream>>>(pred, inst, ws);
    lovaszKernel<<<60, 256, 0, stream>>>(ws, out);
}